// Round 7
// baseline (173.204 us; speedup 1.0000x reference)
//
#include <hip/hip_runtime.h>
#include <cstdint>

#define DEVINL __device__ __forceinline__

// ---------------- problem geometry ----------------
constexpr int NB = 8;        // batch
constexpr int NG = 50;       // gts per image
constexpr int KTOT = 120087; // total anchors per image
constexpr int BK = NB * KTOT;

constexpr int L_W[5]   = {100, 50, 25, 13, 7};
constexpr int L_K[5]   = {90000, 22500, 5625, 1521, 441};
constexpr int L_OFF[5] = {0, 90000, 112500, 118125, 119646};
constexpr int L_WSB[5] = {0, 720000, 900000, 945000, 957168}; // L_OFF * NB

// base anchor tables (float64, matching numpy bit-for-bit)
constexpr double HR_T[3] = {0.7071067811865476, 1.0, 1.4142135623730951}; // sqrt(ratios)
constexpr double WR_T[3] = {1.0 / HR_T[0], 1.0, 1.0 / HR_T[2]};          // 1/sqrt(ratios)
constexpr double SC_T[3] = {4.0, 5.039684199579493, 6.3496042078727974}; // 4*2^(i/3)

// ---------------- device-global scratch ----------------
__device__ float4 g_anc[KTOT];
__device__ double g_accs[256][2];
__device__ unsigned g_ns;
__device__ unsigned g_done;
__device__ unsigned g_gtmax[NB * NG];
__device__ int8_t g_lab[BK];
__device__ __align__(8) int8_t g_lw[BK];
__device__ int8_t g_pos[BK];
__device__ int8_t g_mg[BK];

// ---------------- helpers ----------------
DEVINL unsigned encf(float f) { // monotonic, equality-preserving float->uint
  unsigned u = __float_as_uint(f);
  return (u & 0x80000000u) ? ~u : (u | 0x80000000u);
}
DEVINL int lvl_of(int k) {
  return (k < 90000) ? 0 : (k < 112500) ? 1 : (k < 118125) ? 2 : (k < 119646) ? 3 : 4;
}
// the ONLY IoU expression — identical instruction sequence everywhere
DEVINL float iou_one(float ax0, float ay0, float ax1, float ay1, float areaA,
                     float bx0, float by0, float bx1, float by1, float areaB) {
  float ltx = fmaxf(ax0, bx0);
  float lty = fmaxf(ay0, by0);
  float rbx = fminf(ax1, bx1);
  float rby = fminf(ay1, by1);
  float wx = fmaxf(rbx - ltx, 0.0f);
  float wy = fmaxf(rby - lty, 0.0f);
  float inter = wx * wy;
  return __fdividef(inter, areaA + areaB - inter);
}

// shared f64 anchor math: the ONE expression tree producing anchor f32 coords
DEVINL void wh_f64(int l, int a, double& wsz, double& hsz) {
  int st = 8 << l;
  int ridx = a / 3, sidx = a - ridx * 3;
  double sc = (sidx == 0) ? SC_T[0] : (sidx == 1) ? SC_T[1] : SC_T[2];
  double wr = (ridx == 0) ? WR_T[0] : (ridx == 1) ? WR_T[1] : WR_T[2];
  double hr = (ridx == 0) ? HR_T[0] : (ridx == 1) ? HR_T[1] : HR_T[2];
  wsz = wr * sc * (double)st;
  hsz = hr * sc * (double)st;
}
DEVINL void anchor_from_wh(int l, int xi, int yi, double wsz, double hsz,
                           float& x0, float& y0, float& x1, float& y1) {
  int st = 8 << l;
  double cx = (double)(xi * st), cy = (double)(yi * st);
  x0 = (float)(cx - wsz * 0.5);
  y0 = (float)(cy - hsz * 0.5);
  x1 = (float)(cx + wsz * 0.5);
  y1 = (float)(cy + hsz * 0.5);
}

// ---------------- kernel 0: setup + analytic gt_max (fused, independent) ----
// Blocks [0, NBLK_ANC): init scalars + fill g_anc (f64 math once).
// Blocks [NBLK_ANC, +NB*NG): per-(b,g) gt_max via analytic candidate set.
// The gtmax part recomputes anchors with the SAME f64 expressions (bit-equal
// to g_anc), so the two parts have no data dependency and run concurrently.
constexpr int NBLK_ANC = (KTOT + 255) / 256; // 470

DEVINL int axis_cand(int xi, int i0, int lo, int hi, int Wm1) {
  int c;
  if (xi < 4) c = i0 - 1 + xi;
  else if (xi == 4) c = lo;
  else if (xi == 5) c = lo + 1;
  else if (xi == 6) c = hi - 1;
  else if (xi == 7) c = hi;
  else if (xi == 8) c = 0;
  else c = Wm1;
  return min(max(c, 0), Wm1);
}

__global__ __launch_bounds__(256) void k_setup(const float* __restrict__ tb) {
  if (blockIdx.x < NBLK_ANC) {
    if (blockIdx.x == 0) {
      int t = threadIdx.x;
      g_accs[t][0] = 0.0;
      g_accs[t][1] = 0.0;
      if (t == 0) { g_ns = 0u; g_done = 0u; }
    }
    int k = blockIdx.x * 256 + threadIdx.x;
    if (k >= KTOT) return;
    int l = lvl_of(k);
    int r = k - L_OFF[l];
    int loc = r / 9;
    int a = r - loc * 9;
    int W = L_W[l];
    int y = loc / W;
    int x = loc - y * W;
    double wsz, hsz;
    wh_f64(l, a, wsz, hsz);
    float x0, y0, x1, y1;
    anchor_from_wh(l, x, y, wsz, hsz, x0, y0, x1, y1);
    g_anc[k] = make_float4(x0, y0, x1, y1);
    return;
  }
  // ---- gtmax part ----
  // 1D overlap is concave piecewise-linear in the anchor center and IoU is
  // monotone in the separable intersection, so the constrained grid argmax is
  // among {floor/ceil of box center +/-1} ∪ {inside-validity bounds} ∪ {grid
  // bounds} per axis. Candidates use the SAME f64->f32 anchor expression and
  // the SAME iou_one, so the max is bit-identical to brute force.
  const int bg = blockIdx.x - NBLK_ANC; // b*NG + g
  float4 v = reinterpret_cast<const float4*>(tb)[bg];
  const float bx0 = v.x, by0 = v.y, bx1 = v.z, by1 = v.w;
  const float areaB = (bx1 - bx0) * (by1 - by0);
  const float bcx = 0.5f * (bx0 + bx1), bcy = 0.5f * (by0 + by1);

  float m = -1.0f;
  for (int t = threadIdx.x; t < 4500; t += 256) {
    int l = t / 900;
    int rem = t - l * 900;
    int a = rem / 100;
    int rem2 = rem - a * 100;
    int xi = rem2 / 10;
    int yi = rem2 - xi * 10;
    int W = (l == 0) ? 100 : (l == 1) ? 50 : (l == 2) ? 25 : (l == 3) ? 13 : 7;
    float stf = (float)(8 << l);
    double wsz, hsz;
    wh_f64(l, a, wsz, hsz);
    float whalf = (float)(wsz * 0.5);
    float hhalf = (float)(hsz * 0.5);
    int i0x = (int)floorf(bcx / stf);
    int lox = (int)ceilf(whalf / stf);
    int hix = (int)floorf((800.0f - whalf) / stf);
    int i0y = (int)floorf(bcy / stf);
    int loy = (int)ceilf(hhalf / stf);
    int hiy = (int)floorf((800.0f - hhalf) / stf);
    int cx = axis_cand(xi, i0x, lox, hix, W - 1);
    int cy = axis_cand(yi, i0y, loy, hiy, W - 1);
    float ax0, ay0, ax1, ay1;
    anchor_from_wh(l, cx, cy, wsz, hsz, ax0, ay0, ax1, ay1);
    bool inside = (ax0 >= 0.0f) & (ay0 >= 0.0f) & (ax1 <= 800.0f) & (ay1 <= 800.0f);
    float areaA = (ax1 - ax0) * (ay1 - ay0);
    float iou = inside ? iou_one(ax0, ay0, ax1, ay1, areaA,
                                 bx0, by0, bx1, by1, areaB)
                       : -1.0f;
    m = fmaxf(m, iou);
  }
#pragma unroll
  for (int off = 32; off; off >>= 1) m = fmaxf(m, __shfl_down(m, off));
  __shared__ float s_m[4];
  int lane = threadIdx.x & 63, wid = threadIdx.x >> 6;
  if (lane == 0) s_m[wid] = m;
  __syncthreads();
  if (threadIdx.x == 0) {
    float r = fmaxf(fmaxf(s_m[0], s_m[1]), fmaxf(s_m[2], s_m[3]));
    g_gtmax[bg] = encf(r); // sole writer, no atomic
  }
}

// ---------------- kernel 1: assignment, ballot-compacted gt list ------------
constexpr int APB = 4;
__global__ __launch_bounds__(256) void k_assign(const float* __restrict__ tb,
                                                const int* __restrict__ tcls) {
  const int b = blockIdx.y;
  __shared__ float s_b[NG][8]; // x0,y0,x1,y1,area,qmax
  __shared__ int s_cls[NG];
  __shared__ unsigned s_cnt;
  int tid = threadIdx.x;
  if (tid == 0) s_cnt = 0u;
  if (tid < NG) {
    float4 v = reinterpret_cast<const float4*>(tb)[b * NG + tid];
    s_b[tid][0] = v.x; s_b[tid][1] = v.y; s_b[tid][2] = v.z; s_b[tid][3] = v.w;
    s_b[tid][4] = (v.z - v.x) * (v.w - v.y);
    unsigned gm = g_gtmax[b * NG + tid];
    s_b[tid][5] = (gm > 0x80000000u) ? __uint_as_float(gm ^ 0x80000000u)
                                     : __uint_as_float(0x7FC00000u); // NaN: never ==
    s_cls[tid] = tcls[b * NG + tid];
  }
  __syncthreads();

  const int base = (blockIdx.x * 256 + tid) * APB;
  float Ax0[APB], Ay0[APB], Ax1[APB], Ay1[APB], areaA[APB];
  bool inside[APB];
  float ex0 = __builtin_inff(), ey0 = __builtin_inff();
  float ex1 = -__builtin_inff(), ey1 = -__builtin_inff();
#pragma unroll
  for (int ap = 0; ap < APB; ++ap) {
    int k = base + ap;
    bool valid = k < KTOT;
    float4 A = g_anc[valid ? k : 0];
    bool ins = valid & (A.x >= 0.0f) & (A.y >= 0.0f) & (A.z <= 800.0f) & (A.w <= 800.0f);
    inside[ap] = ins;
    ex0 = fminf(ex0, ins ? A.x : __builtin_inff());
    ey0 = fminf(ey0, ins ? A.y : __builtin_inff());
    ex1 = fmaxf(ex1, ins ? A.z : -__builtin_inff());
    ey1 = fmaxf(ey1, ins ? A.w : -__builtin_inff());
    if (!ins) A = make_float4(-4000.0f, -4000.0f, -3999.0f, -3999.0f); // IoU==0 vs any gt
    Ax0[ap] = A.x; Ay0[ap] = A.y; Ax1[ap] = A.z; Ay1[ap] = A.w;
    areaA[ap] = (A.z - A.x) * (A.w - A.y);
  }
  // wave extent over inside anchors
#pragma unroll
  for (int off = 1; off < 64; off <<= 1) {
    ex0 = fminf(ex0, __shfl_xor(ex0, off));
    ey0 = fminf(ey0, __shfl_xor(ey0, off));
    ex1 = fmaxf(ex1, __shfl_xor(ex1, off));
    ey1 = fmaxf(ey1, __shfl_xor(ey1, off));
  }
  // ballot-compacted active gt list (lane g tests gt g; pruned gts have IoU
  // exactly 0 for every lane -> no observable effect on best/lqg/labels)
  unsigned long long amask;
  {
    int g = tid & 63;
    bool act = false;
    if (g < NG) {
      float ox = fminf(ex1, s_b[g][2]) - fmaxf(ex0, s_b[g][0]);
      float oy = fminf(ey1, s_b[g][3]) - fmaxf(ey0, s_b[g][1]);
      act = (ox > 0.0f) && (oy > 0.0f);
    }
    amask = __ballot(act);
  }

  float best[APB];
  int arg[APB], lqg[APB];
#pragma unroll
  for (int ap = 0; ap < APB; ++ap) { best[ap] = -2.0f; arg[ap] = 0; lqg[ap] = -1; }

  while (amask) { // ascending g preserves first-max / last-g semantics
    int g = __builtin_ctzll(amask);
    amask &= amask - 1;
    float gx0 = s_b[g][0], gy0 = s_b[g][1], gx1 = s_b[g][2], gy1 = s_b[g][3];
    float gar = s_b[g][4], qmx = s_b[g][5];
#pragma unroll
    for (int ap = 0; ap < APB; ++ap) {
      float iou = iou_one(Ax0[ap], Ay0[ap], Ax1[ap], Ay1[ap], areaA[ap],
                          gx0, gy0, gx1, gy1, gar);
      if (iou > best[ap]) { best[ap] = iou; arg[ap] = g; }
      if (iou == qmx) lqg[ap] = g;
    }
  }

  int cnt = 0;
#pragma unroll
  for (int ap = 0; ap < APB; ++ap) {
    int k = base + ap;
    if (k < KTOT) {
      int lab = (best[ap] >= 0.5f) ? 1 : ((best[ap] >= 0.4f) ? -1 : 0);
      int mg = arg[ap];
      if (lqg[ap] >= 0) { lab = 1; mg = lqg[ap]; }
      bool pos = (lab == 1) && inside[ap];
      bool neg = (lab == 0) && inside[ap];
      int l = lvl_of(k);
      int r = k - L_OFF[l];
      int widx = L_WSB[l] + b * L_K[l] + r;
      g_lab[widx] = pos ? (int8_t)s_cls[mg] : (int8_t)0;
      g_lw[widx] = (pos || neg) ? 1 : 0;
      g_pos[widx] = pos ? 1 : 0;
      g_mg[widx] = (int8_t)mg;
      cnt += (pos || neg) ? 1 : 0;
    }
  }
#pragma unroll
  for (int off = 32; off; off >>= 1) cnt += __shfl_down(cnt, off);
  if ((tid & 63) == 0 && cnt) atomicAdd(&s_cnt, (unsigned)cnt);
  __syncthreads();
  if (tid == 0 && s_cnt) atomicAdd(&g_ns, s_cnt);
}

// ---------------- kernel 2: vectorized loss + fused finalize ----------------
// Thread = 4 consecutive pixels x 8 classes of one (b, a) plane:
// 8x float4 cls loads, 4x aligned u64 lw loads, all-static register indexing.
constexpr int G_OFF[6] = {0, 180000, 225000, 236304, 239400, 240336};
constexpr int TOTAL_G = 240336;

template <int HW, int GPL, int KL, int WSB, int LOFF>
DEVINL void level_term4(const float* __restrict__ cls, const float* __restrict__ reg,
                        const float4* __restrict__ tb4, int j, float& vc, float& vb) {
  constexpr int NPG = 9 * GPL;
  int b = j / NPG;
  int rem = j - b * NPG;
  int a = rem / GPL;
  int gi = rem - a * GPL;
  int pix0 = gi * 4;
  const float* cb = cls + (b * 72 + a * 8) * HW + pix0;
  const int8_t* lwb = g_lw + WSB + 8 * (9 * pix0 + a);
  int idxb = WSB + b * KL + 9 * pix0 + a;

  if (pix0 + 4 <= HW) {
    float xs[8][4];
#pragma unroll
    for (int c = 0; c < 8; ++c) {
      float4 v4 = *reinterpret_cast<const float4*>(cb + c * HW);
      xs[c][0] = v4.x; xs[c][1] = v4.y; xs[c][2] = v4.z; xs[c][3] = v4.w;
    }
#pragma unroll
    for (int e = 0; e < 4; ++e) {
      unsigned long long lwq =
          *reinterpret_cast<const unsigned long long*>(lwb + 72 * e);
      if (lwq) {
        int lab = g_lab[idxb + 9 * e];
#pragma unroll
        for (int c = 0; c < 8; ++c) {
          float w = (float)((unsigned)(lwq >> (8 * c)) & 0xffu);
          float x = xs[c][e];
          float t = (lab == c) ? 1.0f : 0.0f;
          float ax = fabsf(x);
          float ex = __expf(-ax);
          vc += (fmaxf(x, 0.0f) - x * t + __logf(1.0f + ex)) * w;
        }
      }
      if (g_pos[idxb + 9 * e]) {
        int mg = g_mg[idxb + 9 * e];
        int q = (pix0 + e) * 9 + a;
        float4 A = g_anc[LOFF + q];
        float aw = A.z - A.x, ah = A.w - A.y;
        float acx = A.x + 0.5f * aw, acy = A.y + 0.5f * ah;
        float4 gb = tb4[b * NG + mg];
        float gw = gb.z - gb.x, gh = gb.w - gb.y;
        float gcx = gb.x + 0.5f * gw, gcy = gb.y + 0.5f * gh;
        const float* rbase = reg + (b * 36 + a * 4) * HW + pix0 + e;
        vb += fabsf(rbase[0] - (gcx - acx) / aw);
        vb += fabsf(rbase[HW] - (gcy - acy) / ah);
        vb += fabsf(rbase[2 * HW] - logf(gw / aw));
        vb += fabsf(rbase[3 * HW] - logf(gh / ah));
      }
    }
  } else { // tail (HW%4==1 levels): scalar, avoids OOB vector loads
    int nrem = HW - pix0;
#pragma unroll
    for (int e = 0; e < 3; ++e) {
      if (e < nrem) {
        unsigned long long lwq =
            *reinterpret_cast<const unsigned long long*>(lwb + 72 * e);
        if (lwq) {
          int lab = g_lab[idxb + 9 * e];
#pragma unroll
          for (int c = 0; c < 8; ++c) {
            float w = (float)((unsigned)(lwq >> (8 * c)) & 0xffu);
            float x = cb[c * HW + e];
            float t = (lab == c) ? 1.0f : 0.0f;
            float ax = fabsf(x);
            float ex = __expf(-ax);
            vc += (fmaxf(x, 0.0f) - x * t + __logf(1.0f + ex)) * w;
          }
        }
        if (g_pos[idxb + 9 * e]) {
          int mg = g_mg[idxb + 9 * e];
          int q = (pix0 + e) * 9 + a;
          float4 A = g_anc[LOFF + q];
          float aw = A.z - A.x, ah = A.w - A.y;
          float acx = A.x + 0.5f * aw, acy = A.y + 0.5f * ah;
          float4 gb = tb4[b * NG + mg];
          float gw = gb.z - gb.x, gh = gb.w - gb.y;
          float gcx = gb.x + 0.5f * gw, gcy = gb.y + 0.5f * gh;
          const float* rbase = reg + (b * 36 + a * 4) * HW + pix0 + e;
          vb += fabsf(rbase[0] - (gcx - acx) / aw);
          vb += fabsf(rbase[HW] - (gcy - acy) / ah);
          vb += fabsf(rbase[2 * HW] - logf(gw / aw));
          vb += fabsf(rbase[3 * HW] - logf(gh / ah));
        }
      }
    }
  }
}

__global__ __launch_bounds__(256) void k_loss(
    const float* __restrict__ c0, const float* __restrict__ c1,
    const float* __restrict__ c2, const float* __restrict__ c3,
    const float* __restrict__ c4, const float* __restrict__ r0,
    const float* __restrict__ r1, const float* __restrict__ r2,
    const float* __restrict__ r3, const float* __restrict__ r4,
    const float* __restrict__ tb, float* __restrict__ out) {
  const float4* tb4 = reinterpret_cast<const float4*>(tb);
  int T = blockIdx.x * 256 + threadIdx.x;
  float vc = 0.0f, vb = 0.0f;
  if (T < TOTAL_G) {
    if (T < G_OFF[1])      level_term4<10000, 2500, 90000, 0, 0>(c0, r0, tb4, T, vc, vb);
    else if (T < G_OFF[2]) level_term4<2500, 625, 22500, 720000, 90000>(c1, r1, tb4, T - G_OFF[1], vc, vb);
    else if (T < G_OFF[3]) level_term4<625, 157, 5625, 900000, 112500>(c2, r2, tb4, T - G_OFF[2], vc, vb);
    else if (T < G_OFF[4]) level_term4<169, 43, 1521, 945000, 118125>(c3, r3, tb4, T - G_OFF[3], vc, vb);
    else                   level_term4<49, 13, 441, 957168, 119646>(c4, r4, tb4, T - G_OFF[4], vc, vb);
  }
#pragma unroll
  for (int off = 32; off; off >>= 1) {
    vc += __shfl_down(vc, off);
    vb += __shfl_down(vb, off);
  }
  __shared__ float sc_[4], sb_[4];
  __shared__ bool s_last;
  int lane = threadIdx.x & 63;
  int wid = threadIdx.x >> 6;
  if (lane == 0) { sc_[wid] = vc; sb_[wid] = vb; }
  __syncthreads();
  if (threadIdx.x == 0) {
    float tc = sc_[0] + sc_[1] + sc_[2] + sc_[3];
    float tbx = sb_[0] + sb_[1] + sb_[2] + sb_[3];
    int slot = blockIdx.x & 255;
    if (tc != 0.0f) atomicAdd(&g_accs[slot][0], (double)tc);
    if (tbx != 0.0f) atomicAdd(&g_accs[slot][1], (double)tbx);
    __threadfence();
    unsigned old = atomicAdd(&g_done, 1u);
    s_last = (old == gridDim.x - 1);
  }
  __syncthreads();
  if (s_last) { // last block: reduce the 256 slots and write outputs
    int t = threadIdx.x;
    double a0 = atomicAdd(&g_accs[t][0], 0.0); // atomic read -> L2-coherent
    double a1 = atomicAdd(&g_accs[t][1], 0.0);
#pragma unroll
    for (int off = 32; off; off >>= 1) {
      a0 += __shfl_down(a0, off);
      a1 += __shfl_down(a1, off);
    }
    __shared__ double s0[4], s1[4];
    if (lane == 0) { s0[wid] = a0; s1[wid] = a1; }
    __syncthreads();
    if (t == 0) {
      double A0 = s0[0] + s0[1] + s0[2] + s0[3];
      double A1 = s1[0] + s1[1] + s1[2] + s1[3];
      double n = (double)g_ns;
      out[0] = (float)(A0 / n);
      out[1] = (float)(A1 / n);
    }
  }
}

// ---------------- launcher ----------------
extern "C" void kernel_launch(void* const* d_in, const int* in_sizes, int n_in,
                              void* d_out, int out_size, void* d_ws, size_t ws_size,
                              hipStream_t stream) {
  // setup_inputs() inserts cls/reg INTERLEAVED: cls0,reg0,cls1,reg1,...,tb,tcls
  const float* c0 = (const float*)d_in[0];
  const float* r0 = (const float*)d_in[1];
  const float* c1 = (const float*)d_in[2];
  const float* r1 = (const float*)d_in[3];
  const float* c2 = (const float*)d_in[4];
  const float* r2 = (const float*)d_in[5];
  const float* c3 = (const float*)d_in[6];
  const float* r3 = (const float*)d_in[7];
  const float* c4 = (const float*)d_in[8];
  const float* r4 = (const float*)d_in[9];
  const float* tb = (const float*)d_in[10];
  const int* tcls = (const int*)d_in[11];
  float* out = (float*)d_out;

  k_setup<<<dim3(NBLK_ANC + NB * NG), dim3(256), 0, stream>>>(tb);
  k_assign<<<dim3((KTOT + 256 * APB - 1) / (256 * APB), NB), dim3(256), 0, stream>>>(tb, tcls);
  k_loss<<<dim3((TOTAL_G + 255) / 256), dim3(256), 0, stream>>>(c0, c1, c2, c3, c4,
                                                                r0, r1, r2, r3, r4, tb, out);
}